// Round 3
// baseline (31.890 us; speedup 1.0000x reference)
//
#include <hip/hip_runtime.h>
#include <hip/hip_bf16.h>

// Problem constants: B=16, S=2048, D=512
// inputs: x [B,S,D] f32, input_ids [B,S] int32, start_token_id int scalar,
//         control_emb [4, D] f32, sequence_emb [1003, D] f32
// output: [B,S,D] f32

#define S_LEN 2048
#define D_DIM 512
#define D4 (D_DIM / 4)            // 128 float4 per row
#define SEQ_START 4
#define NUM_SEQ 1003
#define CS 64                     // positions (rows) per block
#define NCHUNK (S_LEN / CS)       // 32 chunks per batch row
#define THREADS 512               // 8 waves
#define NWAVE (THREADS / 64)
#define PER (S_LEN / THREADS)     // 4 ids per thread in prefix phase

typedef float f4 __attribute__((ext_vector_type(4)));   // nontemporal-friendly

// Fused: per-block prefix recompute (last start-token pos before chunk),
// 64-lane shfl scan for the chunk, then streaming float4 add.
__global__ void __launch_bounds__(THREADS)
alpe_fused_kernel(const f4* __restrict__ x,
                  const f4* __restrict__ ctrl,
                  const f4* __restrict__ seq,
                  const int* __restrict__ ids,
                  const int* __restrict__ start_tok,
                  f4* __restrict__ out) {
    const int b   = blockIdx.x / NCHUNK;
    const int cid = blockIdx.x % NCHUNK;
    const int chunk_start = cid * CS;
    const int t = threadIdx.x;
    const int st = *start_tok;

    __shared__ int wmax[NWAVE];
    __shared__ int codes_s[CS];

    // ---- Phase 1a: per-thread max marker over [0, chunk_start) ----
    int m = -1;
    #pragma unroll
    for (int k = 0; k < PER; ++k) {
        const int j = t * PER + k;
        if (j < chunk_start) {
            const int id = ids[b * S_LEN + j];
            if (id == st && j >= SEQ_START) m = max(m, j);
        }
    }
    // wave reduce (64 lanes)
    #pragma unroll
    for (int off = 32; off >= 1; off >>= 1)
        m = max(m, __shfl_xor(m, off));
    if ((t & 63) == 0) wmax[t >> 6] = m;
    __syncthreads();

    // ---- Phase 1b: wave 0 scans the chunk's own 64 positions ----
    if (t < 64) {
        const int p = chunk_start + t;
        const int id = ids[b * S_LEN + p];
        int mk = (id == st && p >= SEQ_START) ? p : -1;
        // inclusive max-scan across 64 lanes
        #pragma unroll
        for (int off = 1; off < 64; off <<= 1) {
            const int o = __shfl_up(mk, off);
            if (t >= off) mk = max(mk, o);
        }
        int carry = -1;
        #pragma unroll
        for (int w = 0; w < NWAVE; ++w) carry = max(carry, wmax[w]);
        const int last = max(mk, carry);
        int code;
        if (last >= 0) {
            const int rel = p - last;
            code = (rel < NUM_SEQ) ? rel : -1;     // p>=4 here, ctrl impossible
        } else {
            code = (p < SEQ_START) ? (-2 - p) : -1;
        }
        codes_s[t] = code;
    }
    __syncthreads();

    // ---- Phase 2: streaming add over CS x D (8192 float4) ----
    const size_t base4 = ((size_t)(b * S_LEN + chunk_start)) * D4;
    #pragma unroll
    for (int it = 0; it < (CS * D4) / THREADS; ++it) {
        const int j  = it * THREADS + t;
        const int sl = j >> 7;          // /D4
        const int d4 = j & (D4 - 1);
        const int code = codes_s[sl];
        const f4 xv = __builtin_nontemporal_load(&x[base4 + j]);
        f4 e = (f4){0.f, 0.f, 0.f, 0.f};
        if (code >= 0) {
            e = seq[code * D4 + d4];
        } else if (code <= -2) {
            e = ctrl[(-2 - code) * D4 + d4];
        }
        const f4 r = xv + e;
        __builtin_nontemporal_store(r, &out[base4 + j]);
    }
}

extern "C" void kernel_launch(void* const* d_in, const int* in_sizes, int n_in,
                              void* d_out, int out_size, void* d_ws, size_t ws_size,
                              hipStream_t stream) {
    const float* x         = (const float*)d_in[0];
    const int*   input_ids = (const int*)d_in[1];
    const int*   start_tok = (const int*)d_in[2];
    const float* ctrl      = (const float*)d_in[3];
    const float* seq       = (const float*)d_in[4];
    float*       out       = (float*)d_out;

    const int B = in_sizes[1] / S_LEN;          // 16
    const int grid = B * NCHUNK;                // 512 blocks

    alpe_fused_kernel<<<grid, THREADS, 0, stream>>>(
        (const f4*)x, (const f4*)ctrl, (const f4*)seq,
        input_ids, start_tok, (f4*)out);
}

// Round 4
// 27.151 us; speedup vs baseline: 1.1745x; 1.1745x over previous
//
#include <hip/hip_runtime.h>
#include <hip/hip_bf16.h>

// Problem constants: B=16, S=2048, D=512
// inputs: x [B,S,D] f32, input_ids [B,S] int32, start_token_id int scalar,
//         control_emb [4, D] f32, sequence_emb [1003, D] f32
// output: [B,S,D] f32

#define S_LEN 2048
#define D_DIM 512
#define D4 (D_DIM / 4)            // 128 float4 per row
#define SEQ_START 4
#define NUM_SEQ 1003
#define CS 64                     // positions (rows) per block
#define NCHUNK (S_LEN / CS)       // 32 chunks per batch row
#define THREADS 512               // 8 waves
#define NWAVE (THREADS / 64)
#define PER (S_LEN / THREADS)     // 4 ids per thread in prefix phase

typedef float f4 __attribute__((ext_vector_type(4)));

// Fused: per-block prefix recompute (last start-token pos before chunk),
// 64-lane shfl scan for the chunk, then streaming float4 add.
// R4: regular cached loads/stores (no nontemporal) — working set (130 MB)
// fits the 256 MB L3, so cached access lets replays run from L3.
__global__ void __launch_bounds__(THREADS)
alpe_fused_kernel(const f4* __restrict__ x,
                  const f4* __restrict__ ctrl,
                  const f4* __restrict__ seq,
                  const int* __restrict__ ids,
                  const int* __restrict__ start_tok,
                  f4* __restrict__ out) {
    const int b   = blockIdx.x / NCHUNK;
    const int cid = blockIdx.x % NCHUNK;
    const int chunk_start = cid * CS;
    const int t = threadIdx.x;
    const int st = *start_tok;

    __shared__ int wmax[NWAVE];
    __shared__ int codes_s[CS];

    // ---- Phase 1a: per-thread max marker over [0, chunk_start) ----
    int m = -1;
    #pragma unroll
    for (int k = 0; k < PER; ++k) {
        const int j = t * PER + k;
        if (j < chunk_start) {
            const int id = ids[b * S_LEN + j];
            if (id == st && j >= SEQ_START) m = max(m, j);
        }
    }
    #pragma unroll
    for (int off = 32; off >= 1; off >>= 1)
        m = max(m, __shfl_xor(m, off));
    if ((t & 63) == 0) wmax[t >> 6] = m;
    __syncthreads();

    // ---- Phase 1b: wave 0 scans the chunk's own 64 positions ----
    if (t < 64) {
        const int p = chunk_start + t;
        const int id = ids[b * S_LEN + p];
        int mk = (id == st && p >= SEQ_START) ? p : -1;
        #pragma unroll
        for (int off = 1; off < 64; off <<= 1) {
            const int o = __shfl_up(mk, off);
            if (t >= off) mk = max(mk, o);
        }
        int carry = -1;
        #pragma unroll
        for (int w = 0; w < NWAVE; ++w) carry = max(carry, wmax[w]);
        const int last = max(mk, carry);
        int code;
        if (last >= 0) {
            const int rel = p - last;
            code = (rel < NUM_SEQ) ? rel : -1;     // p>=4 here, ctrl impossible
        } else {
            code = (p < SEQ_START) ? (-2 - p) : -1;
        }
        codes_s[t] = code;
    }
    __syncthreads();

    // ---- Phase 2: streaming add over CS x D (8192 float4) ----
    const size_t base4 = ((size_t)(b * S_LEN + chunk_start)) * D4;
    #pragma unroll
    for (int it = 0; it < (CS * D4) / THREADS; ++it) {
        const int j  = it * THREADS + t;
        const int sl = j >> 7;          // /D4
        const int d4 = j & (D4 - 1);
        const int code = codes_s[sl];   // wave-uniform (128 threads share sl)
        const f4 xv = x[base4 + j];
        f4 e = (f4){0.f, 0.f, 0.f, 0.f};
        if (code >= 0) {
            e = seq[code * D4 + d4];
        } else if (code <= -2) {
            e = ctrl[(-2 - code) * D4 + d4];
        }
        out[base4 + j] = xv + e;
    }
}

extern "C" void kernel_launch(void* const* d_in, const int* in_sizes, int n_in,
                              void* d_out, int out_size, void* d_ws, size_t ws_size,
                              hipStream_t stream) {
    const float* x         = (const float*)d_in[0];
    const int*   input_ids = (const int*)d_in[1];
    const int*   start_tok = (const int*)d_in[2];
    const float* ctrl      = (const float*)d_in[3];
    const float* seq       = (const float*)d_in[4];
    float*       out       = (float*)d_out;

    const int B = in_sizes[1] / S_LEN;          // 16
    const int grid = B * NCHUNK;                // 512 blocks

    alpe_fused_kernel<<<grid, THREADS, 0, stream>>>(
        (const f4*)x, (const f4*)ctrl, (const f4*)seq,
        input_ids, start_tok, (f4*)out);
}

// Round 5
// 25.544 us; speedup vs baseline: 1.2484x; 1.0629x over previous
//
#include <hip/hip_runtime.h>
#include <hip/hip_bf16.h>

// Problem constants: B=16, S=2048, D=512
// inputs: x [B,S,D] f32, input_ids [B,S] int32, start_token_id int scalar,
//         control_emb [4, D] f32, sequence_emb [1003, D] f32
// output: [B,S,D] f32

#define S_LEN 2048
#define D4 128                    // float4 per row (D=512)
#define SEQ_START 4
#define NUM_SEQ 1003
#define CS 64                     // positions (rows) per block
#define NCHUNK (S_LEN / CS)       // 32 chunks per batch row
#define THREADS 512               // 8 waves
#define ITERS ((CS * D4) / THREADS)   // 16 f4 per thread
#define PF 8                      // x prefetch depth (registers)
#define IDR 8                     // ids rounds: 8 * 256 = 2048 ids

typedef float f4 __attribute__((ext_vector_type(4)));
typedef int   i4 __attribute__((ext_vector_type(4)));

// Barrier-free fused kernel. Each wave independently computes all 64 codes
// for the block's chunk in registers (redundant across the 8 waves; ids data
// is L1/L2-hot), while an 8-deep register prefetch of x hides HBM latency.
// No LDS, no __syncthreads.
__global__ void __launch_bounds__(THREADS, 4)
alpe_kernel(const f4* __restrict__ x,
            const f4* __restrict__ ctrl,
            const f4* __restrict__ seq,
            const int* __restrict__ ids,
            const int* __restrict__ start_tok,
            f4* __restrict__ out) {
    const int b   = blockIdx.x / NCHUNK;
    const int cid = blockIdx.x % NCHUNK;
    const int chunk_start = cid * CS;
    const int t = threadIdx.x;
    const int w = t >> 6;          // wave id 0..7
    const int l = t & 63;          // lane
    const int st = *start_tok;
    const int* __restrict__ idrow = ids + b * S_LEN;

    // ---- issue ids loads FIRST (they gate the scan; x loads come after so
    // waiting on ids does not drain the x queue) ----
    const int myid = idrow[chunk_start + l];          // my chunk position's id
    i4 idv[IDR];
    #pragma unroll
    for (int r = 0; r < IDR; ++r)
        idv[r] = *(const i4*)&idrow[r * 256 + l * 4];  // full-row prefix, static

    // ---- issue x prefetch (PF deep) ----
    const size_t base4 = (size_t)(b * S_LEN + chunk_start) * D4;
    f4 xp[PF];
    #pragma unroll
    for (int i = 0; i < PF; ++i)
        xp[i] = x[base4 + i * THREADS + t];

    // ---- prefix marker max over [0, chunk_start) ----
    int pm = -1;
    #pragma unroll
    for (int r = 0; r < IDR; ++r) {
        #pragma unroll
        for (int k = 0; k < 4; ++k) {
            const int j = r * 256 + l * 4 + k;
            const int id = idv[r][k];
            if (id == st && j >= SEQ_START && j < chunk_start) pm = max(pm, j);
        }
    }
    #pragma unroll
    for (int off = 32; off >= 1; off >>= 1)
        pm = max(pm, __shfl_xor(pm, off));

    // ---- inclusive max-scan over the chunk's own 64 positions ----
    const int p = chunk_start + l;
    int mk = (myid == st && p >= SEQ_START) ? p : -1;
    #pragma unroll
    for (int off = 1; off < 64; off <<= 1) {
        const int o = __shfl_up(mk, off);
        if (l >= off) mk = max(mk, o);
    }
    const int last = max(mk, pm);
    int mycode;                       // code for row (chunk_start + l)
    if (last >= 0) {
        const int rel = p - last;
        mycode = (rel < NUM_SEQ) ? rel : -1;
    } else {
        mycode = (p < SEQ_START) ? (-2 - p) : -1;
    }

    // ---- streaming add: wave w, iteration it covers row 4*it + (w>>1),
    // half (w&1) of the 128 f4 columns ----
    const int d4w = ((w & 1) << 6) | l;       // my f4 column in the row
    const int rsel = w >> 1;                  // row offset within groups of 4
    #pragma unroll
    for (int it = 0; it < ITERS; ++it) {
        const f4 xv = xp[it & (PF - 1)];
        if (it + PF < ITERS)
            xp[it & (PF - 1)] = x[base4 + (it + PF) * THREADS + t];
        const int code = __shfl(mycode, 4 * it + rsel);   // wave-uniform
        f4 e = (f4){0.f, 0.f, 0.f, 0.f};
        if (code >= 0) {
            e = seq[code * D4 + d4w];
        } else if (code <= -2) {
            e = ctrl[(-2 - code) * D4 + d4w];
        }
        out[base4 + it * THREADS + t] = xv + e;
    }
}

extern "C" void kernel_launch(void* const* d_in, const int* in_sizes, int n_in,
                              void* d_out, int out_size, void* d_ws, size_t ws_size,
                              hipStream_t stream) {
    const float* x         = (const float*)d_in[0];
    const int*   input_ids = (const int*)d_in[1];
    const int*   start_tok = (const int*)d_in[2];
    const float* ctrl      = (const float*)d_in[3];
    const float* seq       = (const float*)d_in[4];
    float*       out       = (float*)d_out;

    const int B = in_sizes[1] / S_LEN;          // 16
    const int grid = B * NCHUNK;                // 512 blocks

    alpe_kernel<<<grid, THREADS, 0, stream>>>(
        (const f4*)x, (const f4*)ctrl, (const f4*)seq,
        input_ids, start_tok, (f4*)out);
}